// Round 12
// baseline (140.606 us; speedup 1.0000x reference)
//
#include <hip/hip_runtime.h>

// TwelveSitesNN2 R10: R9 + (a) dup-row h1 (20 rows/b) so all layer-2 neighbor
// reads are base+immediate (kills w12 address VALU), (b) PART->pool barrier
// replaced by wave_barrier (intra-wave exchange, DS in-order), LDS 25.6KB.

#define LNUM 63
#define BT 16
#define NBT 128   // 2048 / BT
#define WSL 19968 // ushorts per l in ws: [w2T 64x104][fw1T 64x136][fw2T 64x72] (f16)

typedef __attribute__((ext_vector_type(8))) _Float16 half8;
typedef __attribute__((ext_vector_type(2))) _Float16 half2v;
typedef __attribute__((ext_vector_type(4))) float floatx4;
typedef __attribute__((ext_vector_type(4))) unsigned uint4v;

static __device__ __forceinline__ unsigned cvtpk(float a, float b) {
    return __builtin_bit_cast(unsigned, __builtin_amdgcn_cvt_pkrtz(a, b));  // 1 VALU op
}
static __device__ __forceinline__ half2v u2h(unsigned u) { return __builtin_bit_cast(half2v, u); }
static __device__ __forceinline__ float hlo16(unsigned short s) {
    return (float)__builtin_bit_cast(_Float16, s);
}
static __device__ __forceinline__ int w12(int v) { return v >= 12 ? v - 12 : v; }
static __device__ __forceinline__ float2 add2(float2 a, float2 b) { return make_float2(a.x + b.x, a.y + b.y); }

// LDS (U: 6400 dw = 25.6 KB):
//   phase1 : h1 [16 b][20 rows][20 dw] (row r: r<4 -> site r+8 dup,
//            4..15 -> site r-4, 16..19 -> site r-16 dup)                  @0
//   phase2 : PART [1024 u=(b*64+ch)][3] (f16 sum,max per dword)           @0 (overlay)
//            POOLED [16 b][68 dw] (k'-interleaved mean/max f16)           @3200
//   phase3 : POOL2 ush@0 [16][72], G2 ush@1280 [16][72]
#define O_POOLDW 3200
#define O_POOLUS 6400
#define O_POOL2  0
#define O_G2     1280

// prep: grid (LNUM, 3), coalesced float4 reads -> LDS transpose -> coalesced
// dword writes. Region 0: w2T [o][52dw]; 1: fw1T [o][68dw] k'-interleaved;
// 2: fw2T [o][36dw].
__global__ void prep(const float* __restrict__ w2, const float* __restrict__ fw1,
                     const float* __restrict__ fw2, unsigned short* __restrict__ ws) {
    __shared__ float S[8192];
    const int l = blockIdx.x, r = blockIdx.y, t = threadIdx.x;
    if (r == 0) {
        const float4* src = (const float4*)(w2 + (size_t)l * 6144);   // [96][64]
        #pragma unroll
        for (int j = 0; j < 6; ++j) *(float4*)(S + 4 * (t + 256 * j)) = src[t + 256 * j];
        __syncthreads();
        unsigned* dst = (unsigned*)(ws + (size_t)l * WSL);            // 3328 dw
        #pragma unroll
        for (int j = 0; j < 13; ++j) {
            int i = j * 256 + t, o = i / 52, cp = i - 52 * o, c = 2 * cp;
            dst[i] = cvtpk(S[c * 64 + o], S[c * 64 + 64 + o]);
        }
    } else if (r == 1) {
        const float4* src = (const float4*)(fw1 + (size_t)l * 8192);  // [128][64]
        #pragma unroll
        for (int j = 0; j < 8; ++j) *(float4*)(S + 4 * (t + 256 * j)) = src[t + 256 * j];
        __syncthreads();
        unsigned* dst = (unsigned*)(ws + (size_t)l * WSL + 6656);     // 4352 dw
        #pragma unroll
        for (int j = 0; j < 17; ++j) {
            int i = j * 256 + t, o = i / 68, cp = i - 68 * o;
            dst[i] = cvtpk(S[cp * 64 + o], S[(64 + cp) * 64 + o]);    // k'-interleave
        }
    } else {
        const float4* src = (const float4*)(fw2 + (size_t)l * 4096);  // [64][64]
        #pragma unroll
        for (int j = 0; j < 4; ++j) *(float4*)(S + 4 * (t + 256 * j)) = src[t + 256 * j];
        __syncthreads();
        unsigned* dst = (unsigned*)(ws + (size_t)l * WSL + 15360);    // 2304 dw
        #pragma unroll
        for (int j = 0; j < 9; ++j) {
            int i = j * 256 + t, o = i / 36, cp = i - 36 * o, c = 2 * cp;
            dst[i] = cvtpk(S[c * 64 + o], S[c * 64 + 64 + o]);
        }
    }
}

__global__ __launch_bounds__(256, 4) void fused_nn(
    const float* __restrict__ zs,  const float* __restrict__ w1,
    const float* __restrict__ fb1, const float* __restrict__ fb2,
    const float* __restrict__ fw3, const float* __restrict__ fb3,
    const unsigned short* __restrict__ ws,
    float* __restrict__ out)
{
    __shared__ __align__(16) unsigned U[6400];
    unsigned short* USH = (unsigned short*)U;

    const int t    = threadIdx.x;
    const int lane = t & 63;
    const int wv   = t >> 6;
    const int n    = lane & 15;
    const int quad = lane >> 4;
    const int l    = blockIdx.x / NBT;
    const int b0   = (blockIdx.x % NBT) * BT;

    // ---------------- layer 1, thread-local; h1 with dup wrap rows ----------------
    {
        const int b = t >> 4, cpair = t & 15, c0 = cpair * 2;
        const float* xb = zs + ((size_t)(b0 + b) * LNUM + l) * 24;
        float4 xq[6];
        #pragma unroll
        for (int q = 0; q < 6; ++q) xq[q] = *(const float4*)(xb + q * 4);
        float2 xv[12], xr[12], xA[12], xB[12];
        #pragma unroll
        for (int s = 0; s < 12; ++s)
            xv[s] = (s & 1) ? make_float2(xq[s >> 1].z, xq[s >> 1].w)
                            : make_float2(xq[s >> 1].x, xq[s >> 1].y);
        #pragma unroll
        for (int s = 0; s < 12; ++s) xr[s] = add2(xv[w12(s + 1)], xv[w12(s + 11)]);
        #pragma unroll
        for (int s = 0; s < 12; ++s) {
            xA[s] = add2(xr[w12(s + 2)], xr[w12(s + 10)]);
            xB[s] = add2(xr[w12(s + 3)], xr[w12(s + 9)]);
        }
        const float* wl = w1 + (size_t)l * 192 + c0;
        const float2 w0  = *(const float2*)(wl);
        const float2 w1v = *(const float2*)(wl + 32);
        const float2 w2v = *(const float2*)(wl + 64);
        const float2 w3v = *(const float2*)(wl + 96);
        const float2 w4v = *(const float2*)(wl + 128);
        const float2 w5v = *(const float2*)(wl + 160);
        unsigned* hb = U + b * 400 + cpair;
        #pragma unroll
        for (int s = 0; s < 12; ++s) {
            float hx = xv[s].x*w0.x + xv[s].y*w1v.x + xA[s].x*w2v.x + xA[s].y*w3v.x
                     + xB[s].x*w4v.x + xB[s].y*w5v.x;
            float hy = xv[s].x*w0.y + xv[s].y*w1v.y + xA[s].x*w2v.y + xA[s].y*w3v.y
                     + xB[s].x*w4v.y + xB[s].y*w5v.y;
            unsigned pk = cvtpk(fmaxf(hx, 0.f), fmaxf(hy, 0.f));
            hb[(4 + s) * 20] = pk;
            if (s <= 3) hb[(16 + s) * 20] = pk;   // top dup (sites 0..3)
            if (s >= 8) hb[(s - 8) * 20] = pk;    // bottom dup (sites 8..11)
        }
    }
    // hoist fc bias loads (hide VMEM latency behind layer 2)
    const float bias1 = fb1[(size_t)l * 64 + wv * 16 + n];
    const float bias2 = fb2[(size_t)l * 64 + wv * 16 + n];
    __syncthreads();

    // ---------------- layer 2: MFMA f16 (M=192,K=96,N=64); imm-offset sections ----------------
    floatx4 acc[3][4];
    #pragma unroll
    for (int mi = 0; mi < 3; ++mi)
        #pragma unroll
        for (int nt = 0; nt < 4; ++nt) acc[mi][nt] = (floatx4){0.f, 0.f, 0.f, 0.f};
    {
        const unsigned* hbase[3];
        #pragma unroll
        for (int mi = 0; mi < 3; ++mi) {
            int row = 48 * wv + 16 * mi + n;
            int bi = row / 12, si = row - 12 * bi;
            hbase[mi] = U + bi * 400 + (4 + si) * 20 + quad * 4;
        }
        const uint4v* w2q = (const uint4v*)(ws + (size_t)l * WSL);
        #pragma unroll
        for (int ks = 0; ks < 3; ++ks) {
            uint4v bw[4];
            #pragma unroll
            for (int nt = 0; nt < 4; ++nt)
                bw[nt] = w2q[(nt * 16 + n) * 13 + ks * 4 + quad];
            half8 af[3];
            #pragma unroll
            for (int mi = 0; mi < 3; ++mi) {
                const unsigned* hb = hbase[mi];
                if (ks == 0) {
                    af[mi] = *(const half8*)(hb);
                } else if (ks == 1) {   // sites s+1, s-1, s+3, s-3 -> rows +-1, +-3
                    half8 l0 = *(const half8*)(hb + 20);
                    half8 l1 = *(const half8*)(hb - 20);
                    half8 l2 = *(const half8*)(hb + 60);
                    half8 l3 = *(const half8*)(hb - 60);
                    af[mi] = (l0 + l1) + (l2 + l3);
                } else {                // sites s+2, s-2, s+4, s-4 -> rows +-2, +-4
                    half8 l0 = *(const half8*)(hb + 40);
                    half8 l1 = *(const half8*)(hb - 40);
                    half8 l2 = *(const half8*)(hb + 80);
                    half8 l3 = *(const half8*)(hb - 80);
                    af[mi] = (l0 + l1) + (l2 + l3);
                }
            }
            #pragma unroll
            for (int mi = 0; mi < 3; ++mi)
                #pragma unroll
                for (int nt = 0; nt < 4; ++nt)
                    acc[mi][nt] = __builtin_amdgcn_mfma_f32_16x16x32_f16(
                        af[mi], __builtin_bit_cast(half8, bw[nt]), acc[mi][nt], 0, 0, 0);
        }
    }
    __syncthreads();   // h1 reads done -> PART overlays

    // ---------------- register pool partials: relu + sum4/max4 -> PART ----------------
    #pragma unroll
    for (int mi = 0; mi < 3; ++mi) {
        const int rr = 48 * wv + 16 * mi + 4 * quad;   // 4 rows, all within one b
        const int bq = rr / 12;
        const int chk = (rr - 12 * bq) >> 2;
        #pragma unroll
        for (int nt = 0; nt < 4; ++nt) {
            const int ch = nt * 16 + n;
            float r0 = fmaxf(acc[mi][nt][0], 0.f), r1 = fmaxf(acc[mi][nt][1], 0.f);
            float r2 = fmaxf(acc[mi][nt][2], 0.f), r3 = fmaxf(acc[mi][nt][3], 0.f);
            float sm = (r0 + r1) + (r2 + r3);
            float mx = fmaxf(fmaxf(r0, r1), fmaxf(r2, r3));
            U[(bq * 64 + ch) * 3 + chk] = cvtpk(sm, mx);
        }
    }
    // PART write->read is intra-wave (writer b-range 4wv..4wv+3 == reader b = t>>4):
    // DS ops complete in order per wave; only prevent compiler reordering.
    __builtin_amdgcn_wave_barrier();

    // ---------------- pool-final: 3 b128 reads, f16 combine -> POOLED ----------------
    {
        const unsigned* p = U + t * 12;                // units 4t..4t+3
        uint4v q0 = *(const uint4v*)(p);
        uint4v q1 = *(const uint4v*)(p + 4);
        uint4v q2 = *(const uint4v*)(p + 8);
        unsigned arr[12] = {q0.x, q0.y, q0.z, q0.w, q1.x, q1.y, q1.z, q1.w,
                            q2.x, q2.y, q2.z, q2.w};
        const int b = t >> 4, ch0 = (t * 4) & 63;
        const _Float16 inv12 = (_Float16)(1.0f / 12.0f);
        unsigned pk[4];
        #pragma unroll
        for (int j = 0; j < 4; ++j) {
            half2v d0 = u2h(arr[3 * j]), d1 = u2h(arr[3 * j + 1]), d2 = u2h(arr[3 * j + 2]);
            _Float16 s = (d0[0] + d1[0]) + d2[0];
            _Float16 m0 = d0[1] > d1[1] ? d0[1] : d1[1];
            _Float16 m  = m0 > d2[1] ? m0 : d2[1];
            half2v pm;
            pm[0] = s * inv12;
            pm[1] = m;
            pk[j] = __builtin_bit_cast(unsigned, pm);
        }
        uint2 w01 = make_uint2(pk[0], pk[1]), w23 = make_uint2(pk[2], pk[3]);
        *(uint2*)(U + O_POOLDW + b * 68 + ch0)     = w01;
        *(uint2*)(U + O_POOLDW + b * 68 + ch0 + 2) = w23;
    }
    __syncthreads();

    // ---------------- fc1: MFMA (M=16, K=128, N=64), B from ws (k'-reordered) ----------------
    {
        const int o = wv * 16 + n;
        floatx4 a1 = (floatx4){bias1, bias1, bias1, bias1};
        const uint4v* f1q = (const uint4v*)(ws + (size_t)l * WSL + 6656);
        #pragma unroll
        for (int ks = 0; ks < 4; ++ks) {
            half8 av = *(const half8*)(USH + O_POOLUS + n * 136 + ks * 32 + quad * 8);
            uint4v bw = f1q[o * 17 + ks * 4 + quad];
            a1 = __builtin_amdgcn_mfma_f32_16x16x32_f16(av, __builtin_bit_cast(half8, bw), a1, 0, 0, 0);
        }
        #pragma unroll
        for (int i = 0; i < 2; ++i) {
            unsigned pk = cvtpk(fmaxf(a1[2 * i], 0.f), fmaxf(a1[2 * i + 1], 0.f));
            USH[O_POOL2 + (quad * 4 + 2 * i)     * 72 + o] = (unsigned short)(pk & 0xffffu);
            USH[O_POOL2 + (quad * 4 + 2 * i + 1) * 72 + o] = (unsigned short)(pk >> 16);
        }
    }
    __syncthreads();

    // ---------------- fc2: MFMA (M=16, K=64, N=64), B from ws ----------------
    {
        const int o = wv * 16 + n;
        floatx4 a2 = (floatx4){bias2, bias2, bias2, bias2};
        const uint4v* f2q = (const uint4v*)(ws + (size_t)l * WSL + 15360);
        #pragma unroll
        for (int ks = 0; ks < 2; ++ks) {
            half8 av = *(const half8*)(USH + O_POOL2 + n * 72 + ks * 32 + quad * 8);
            uint4v bw = f2q[o * 9 + ks * 4 + quad];
            a2 = __builtin_amdgcn_mfma_f32_16x16x32_f16(av, __builtin_bit_cast(half8, bw), a2, 0, 0, 0);
        }
        #pragma unroll
        for (int i = 0; i < 2; ++i) {
            unsigned pk = cvtpk(fmaxf(a2[2 * i], 0.f), fmaxf(a2[2 * i + 1], 0.f));
            USH[O_G2 + (quad * 4 + 2 * i)     * 72 + o] = (unsigned short)(pk & 0xffffu);
            USH[O_G2 + (quad * 4 + 2 * i + 1) * 72 + o] = (unsigned short)(pk >> 16);
        }
    }
    __syncthreads();

    // ---------------- fc3 (K=64) + output ----------------
    if (t < 16) {
        float a = fb3[l];
        const float* w3 = fw3 + (size_t)l * 64;
        #pragma unroll
        for (int c4 = 0; c4 < 16; ++c4) {
            uint2 u2 = *(const uint2*)(USH + O_G2 + t * 72 + c4 * 4);
            float4 w = *(const float4*)(w3 + c4 * 4);
            a += hlo16((unsigned short)(u2.x & 0xffff)) * w.x
               + hlo16((unsigned short)(u2.x >> 16))    * w.y
               + hlo16((unsigned short)(u2.y & 0xffff)) * w.z
               + hlo16((unsigned short)(u2.y >> 16))    * w.w;
        }
        out[(size_t)(b0 + t) * LNUM + l] = a;
    }
}

extern "C" void kernel_launch(void* const* d_in, const int* in_sizes, int n_in,
                              void* d_out, int out_size, void* d_ws, size_t ws_size,
                              hipStream_t stream) {
    const float* zs  = (const float*)d_in[0];
    const float* w1  = (const float*)d_in[1];
    const float* w2  = (const float*)d_in[2];
    const float* fw1 = (const float*)d_in[3];
    const float* fb1 = (const float*)d_in[4];
    const float* fw2 = (const float*)d_in[5];
    const float* fb2 = (const float*)d_in[6];
    const float* fw3 = (const float*)d_in[7];
    const float* fb3 = (const float*)d_in[8];
    float* out = (float*)d_out;
    unsigned short* ws = (unsigned short*)d_ws;

    hipLaunchKernelGGL(prep, dim3(LNUM, 3), dim3(256), 0, stream, w2, fw1, fw2, ws);
    hipLaunchKernelGGL(fused_nn, dim3(LNUM * NBT), dim3(256), 0, stream,
                       zs, w1, fb1, fb2, fw3, fb3, ws, out);
}

// Round 13
// 133.663 us; speedup vs baseline: 1.0519x; 1.0519x over previous
//
#include <hip/hip_runtime.h>

// TwelveSitesNN2 R11: exact R9 structure (best, 64.0us) + two latency fixes:
// (1) all 12 w2 B-fragments prefetched before the first barrier (VMEM hidden
//     behind layer-1 compute; 48 extra VGPRs, 123 < 128 cap),
// (2) PART->pool full barrier replaced by wave_barrier (intra-wave exchange).

#define LNUM 63
#define BT 16
#define NBT 128   // 2048 / BT
#define WSL 19968 // ushorts per l in ws: [w2T 64x104][fw1T 64x136][fw2T 64x72] (f16)

typedef __attribute__((ext_vector_type(8))) _Float16 half8;
typedef __attribute__((ext_vector_type(2))) _Float16 half2v;
typedef __attribute__((ext_vector_type(4))) float floatx4;
typedef __attribute__((ext_vector_type(4))) unsigned uint4v;

static __device__ __forceinline__ unsigned cvtpk(float a, float b) {
    return __builtin_bit_cast(unsigned, __builtin_amdgcn_cvt_pkrtz(a, b));  // 1 VALU op
}
static __device__ __forceinline__ half2v u2h(unsigned u) { return __builtin_bit_cast(half2v, u); }
static __device__ __forceinline__ float hlo16(unsigned short s) {
    return (float)__builtin_bit_cast(_Float16, s);
}
static __device__ __forceinline__ int w12(int v) { return v >= 12 ? v - 12 : v; }
static __device__ __forceinline__ float2 add2(float2 a, float2 b) { return make_float2(a.x + b.x, a.y + b.y); }

// LDS layout of fused_nn, dword units (U: 4160 dw = 16640 B):
//   phase1 : h1 [192 rows][20 dw] (16 used: 32 f16 ch; cols 16-19 pad)   @0
//   phase2 : PART [1024 u=(b*64+ch)][3 chunks] (f16 sum,max per dword)    @0 (overlay)
//            POOLED [16 b][68 dw] (k'-interleaved mean/max f16)           @3072
//   phase3 : POOL2 ush@0 [16][72], G2 ush@1280 [16][72] (overlay PART)
#define O_POOLDW 3072
#define O_POOLUS 6144
#define O_POOL2  0
#define O_G2     1280

// prep: grid (LNUM, 3), coalesced float4 reads -> LDS transpose -> coalesced
// dword writes. Region 0: w2T [o][52dw]; 1: fw1T [o][68dw] k'-interleaved;
// 2: fw2T [o][36dw].
__global__ void prep(const float* __restrict__ w2, const float* __restrict__ fw1,
                     const float* __restrict__ fw2, unsigned short* __restrict__ ws) {
    __shared__ float S[8192];
    const int l = blockIdx.x, r = blockIdx.y, t = threadIdx.x;
    if (r == 0) {
        const float4* src = (const float4*)(w2 + (size_t)l * 6144);   // [96][64]
        #pragma unroll
        for (int j = 0; j < 6; ++j) *(float4*)(S + 4 * (t + 256 * j)) = src[t + 256 * j];
        __syncthreads();
        unsigned* dst = (unsigned*)(ws + (size_t)l * WSL);            // 3328 dw
        #pragma unroll
        for (int j = 0; j < 13; ++j) {
            int i = j * 256 + t, o = i / 52, cp = i - 52 * o, c = 2 * cp;
            dst[i] = cvtpk(S[c * 64 + o], S[c * 64 + 64 + o]);
        }
    } else if (r == 1) {
        const float4* src = (const float4*)(fw1 + (size_t)l * 8192);  // [128][64]
        #pragma unroll
        for (int j = 0; j < 8; ++j) *(float4*)(S + 4 * (t + 256 * j)) = src[t + 256 * j];
        __syncthreads();
        unsigned* dst = (unsigned*)(ws + (size_t)l * WSL + 6656);     // 4352 dw
        #pragma unroll
        for (int j = 0; j < 17; ++j) {
            int i = j * 256 + t, o = i / 68, cp = i - 68 * o;
            dst[i] = cvtpk(S[cp * 64 + o], S[(64 + cp) * 64 + o]);    // k'-interleave
        }
    } else {
        const float4* src = (const float4*)(fw2 + (size_t)l * 4096);  // [64][64]
        #pragma unroll
        for (int j = 0; j < 4; ++j) *(float4*)(S + 4 * (t + 256 * j)) = src[t + 256 * j];
        __syncthreads();
        unsigned* dst = (unsigned*)(ws + (size_t)l * WSL + 15360);    // 2304 dw
        #pragma unroll
        for (int j = 0; j < 9; ++j) {
            int i = j * 256 + t, o = i / 36, cp = i - 36 * o, c = 2 * cp;
            dst[i] = cvtpk(S[c * 64 + o], S[c * 64 + 64 + o]);
        }
    }
}

__global__ __launch_bounds__(256, 4) void fused_nn(
    const float* __restrict__ zs,  const float* __restrict__ w1,
    const float* __restrict__ fb1, const float* __restrict__ fb2,
    const float* __restrict__ fw3, const float* __restrict__ fb3,
    const unsigned short* __restrict__ ws,
    float* __restrict__ out)
{
    __shared__ __align__(16) unsigned U[4160];
    unsigned short* USH = (unsigned short*)U;

    const int t    = threadIdx.x;
    const int lane = t & 63;
    const int wv   = t >> 6;
    const int n    = lane & 15;
    const int quad = lane >> 4;
    const int l    = blockIdx.x / NBT;
    const int b0   = (blockIdx.x % NBT) * BT;

    // prefetch all layer-2 B fragments (global/L2) — independent of LDS h1
    uint4v bwp[3][4];
    {
        const uint4v* w2q = (const uint4v*)(ws + (size_t)l * WSL);
        #pragma unroll
        for (int ks = 0; ks < 3; ++ks)
            #pragma unroll
            for (int nt = 0; nt < 4; ++nt)
                bwp[ks][nt] = w2q[(nt * 16 + n) * 13 + ks * 4 + quad];
    }

    // ---------------- layer 1, thread-local; write h1 only ----------------
    {
        const int b = t >> 4, cpair = t & 15, c0 = cpair * 2;
        const float* xb = zs + ((size_t)(b0 + b) * LNUM + l) * 24;
        float4 xq[6];
        #pragma unroll
        for (int q = 0; q < 6; ++q) xq[q] = *(const float4*)(xb + q * 4);
        float2 xv[12], xr[12], xA[12], xB[12];
        #pragma unroll
        for (int s = 0; s < 12; ++s)
            xv[s] = (s & 1) ? make_float2(xq[s >> 1].z, xq[s >> 1].w)
                            : make_float2(xq[s >> 1].x, xq[s >> 1].y);
        #pragma unroll
        for (int s = 0; s < 12; ++s) xr[s] = add2(xv[w12(s + 1)], xv[w12(s + 11)]);
        #pragma unroll
        for (int s = 0; s < 12; ++s) {
            xA[s] = add2(xr[w12(s + 2)], xr[w12(s + 10)]);
            xB[s] = add2(xr[w12(s + 3)], xr[w12(s + 9)]);
        }
        const float* wl = w1 + (size_t)l * 192 + c0;
        const float2 w0  = *(const float2*)(wl);
        const float2 w1v = *(const float2*)(wl + 32);
        const float2 w2v = *(const float2*)(wl + 64);
        const float2 w3v = *(const float2*)(wl + 96);
        const float2 w4v = *(const float2*)(wl + 128);
        const float2 w5v = *(const float2*)(wl + 160);
        #pragma unroll
        for (int s = 0; s < 12; ++s) {
            float hx = xv[s].x*w0.x + xv[s].y*w1v.x + xA[s].x*w2v.x + xA[s].y*w3v.x
                     + xB[s].x*w4v.x + xB[s].y*w5v.x;
            float hy = xv[s].x*w0.y + xv[s].y*w1v.y + xA[s].x*w2v.y + xA[s].y*w3v.y
                     + xB[s].x*w4v.y + xB[s].y*w5v.y;
            U[(b * 12 + s) * 20 + cpair] = cvtpk(fmaxf(hx, 0.f), fmaxf(hy, 0.f));
        }
    }
    // hoist fc bias loads (hide VMEM latency behind layer 2)
    const float bias1 = fb1[(size_t)l * 64 + wv * 16 + n];
    const float bias2 = fb2[(size_t)l * 64 + wv * 16 + n];
    __syncthreads();

    // ---------------- layer 2: MFMA f16 (M=192,K=96,N=64); sections on the fly ----------------
    floatx4 acc[3][4];
    #pragma unroll
    for (int mi = 0; mi < 3; ++mi)
        #pragma unroll
        for (int nt = 0; nt < 4; ++nt) acc[mi][nt] = (floatx4){0.f, 0.f, 0.f, 0.f};
    {
        int bi[3], si[3];
        #pragma unroll
        for (int mi = 0; mi < 3; ++mi) {
            int row = 48 * wv + 16 * mi + n;
            bi[mi] = row / 12;
            si[mi] = row - 12 * bi[mi];
        }
        const int q4 = quad * 4;
        const int dA[4] = {1, 11, 3, 9};
        const int dB[4] = {2, 10, 4, 8};
        #pragma unroll
        for (int ks = 0; ks < 3; ++ks) {
            half8 af[3];
            #pragma unroll
            for (int mi = 0; mi < 3; ++mi) {
                const int rb = bi[mi] * 12, s = si[mi];
                if (ks == 0) {
                    af[mi] = *(const half8*)(U + (rb + s) * 20 + q4);
                } else {
                    const int* d = (ks == 1) ? dA : dB;
                    half8 l0 = *(const half8*)(U + (rb + w12(s + d[0])) * 20 + q4);
                    half8 l1 = *(const half8*)(U + (rb + w12(s + d[1])) * 20 + q4);
                    half8 l2 = *(const half8*)(U + (rb + w12(s + d[2])) * 20 + q4);
                    half8 l3 = *(const half8*)(U + (rb + w12(s + d[3])) * 20 + q4);
                    af[mi] = (l0 + l1) + (l2 + l3);
                }
            }
            #pragma unroll
            for (int mi = 0; mi < 3; ++mi)
                #pragma unroll
                for (int nt = 0; nt < 4; ++nt)
                    acc[mi][nt] = __builtin_amdgcn_mfma_f32_16x16x32_f16(
                        af[mi], __builtin_bit_cast(half8, bwp[ks][nt]), acc[mi][nt], 0, 0, 0);
        }
    }
    __syncthreads();   // h1 reads done -> PART overlays

    // ---------------- register pool partials: relu + sum4/max4 -> PART ----------------
    #pragma unroll
    for (int mi = 0; mi < 3; ++mi) {
        const int rr = 48 * wv + 16 * mi + 4 * quad;   // 4 rows, all within one b
        const int bq = rr / 12;
        const int chk = (rr - 12 * bq) >> 2;
        #pragma unroll
        for (int nt = 0; nt < 4; ++nt) {
            const int ch = nt * 16 + n;
            float r0 = fmaxf(acc[mi][nt][0], 0.f), r1 = fmaxf(acc[mi][nt][1], 0.f);
            float r2 = fmaxf(acc[mi][nt][2], 0.f), r3 = fmaxf(acc[mi][nt][3], 0.f);
            float sm = (r0 + r1) + (r2 + r3);
            float mx = fmaxf(fmaxf(r0, r1), fmaxf(r2, r3));
            U[(bq * 64 + ch) * 3 + chk] = cvtpk(sm, mx);
        }
    }
    // PART write->read is intra-wave (writer b-range 4wv..4wv+3 == reader b = t>>4):
    // DS ops complete in order per wave; only prevent compiler reordering.
    __builtin_amdgcn_wave_barrier();

    // ---------------- pool-final: 3 b128 reads, f16 combine -> POOLED ----------------
    {
        const unsigned* p = U + t * 12;                // units 4t..4t+3
        uint4v q0 = *(const uint4v*)(p);
        uint4v q1 = *(const uint4v*)(p + 4);
        uint4v q2 = *(const uint4v*)(p + 8);
        unsigned arr[12] = {q0.x, q0.y, q0.z, q0.w, q1.x, q1.y, q1.z, q1.w,
                            q2.x, q2.y, q2.z, q2.w};
        const int b = t >> 4, ch0 = (t * 4) & 63;
        const _Float16 inv12 = (_Float16)(1.0f / 12.0f);
        unsigned pk[4];
        #pragma unroll
        for (int j = 0; j < 4; ++j) {
            half2v d0 = u2h(arr[3 * j]), d1 = u2h(arr[3 * j + 1]), d2 = u2h(arr[3 * j + 2]);
            _Float16 s = (d0[0] + d1[0]) + d2[0];
            _Float16 m0 = d0[1] > d1[1] ? d0[1] : d1[1];
            _Float16 m  = m0 > d2[1] ? m0 : d2[1];
            half2v pm;
            pm[0] = s * inv12;
            pm[1] = m;
            pk[j] = __builtin_bit_cast(unsigned, pm);
        }
        uint2 w01 = make_uint2(pk[0], pk[1]), w23 = make_uint2(pk[2], pk[3]);
        *(uint2*)(U + O_POOLDW + b * 68 + ch0)     = w01;
        *(uint2*)(U + O_POOLDW + b * 68 + ch0 + 2) = w23;
    }
    __syncthreads();

    // ---------------- fc1: MFMA (M=16, K=128, N=64), B from ws (k'-reordered) ----------------
    {
        const int o = wv * 16 + n;
        floatx4 a1 = (floatx4){bias1, bias1, bias1, bias1};
        const uint4v* f1q = (const uint4v*)(ws + (size_t)l * WSL + 6656);
        #pragma unroll
        for (int ks = 0; ks < 4; ++ks) {
            half8 av = *(const half8*)(USH + O_POOLUS + n * 136 + ks * 32 + quad * 8);
            uint4v bw = f1q[o * 17 + ks * 4 + quad];
            a1 = __builtin_amdgcn_mfma_f32_16x16x32_f16(av, __builtin_bit_cast(half8, bw), a1, 0, 0, 0);
        }
        #pragma unroll
        for (int i = 0; i < 2; ++i) {
            unsigned pk = cvtpk(fmaxf(a1[2 * i], 0.f), fmaxf(a1[2 * i + 1], 0.f));
            USH[O_POOL2 + (quad * 4 + 2 * i)     * 72 + o] = (unsigned short)(pk & 0xffffu);
            USH[O_POOL2 + (quad * 4 + 2 * i + 1) * 72 + o] = (unsigned short)(pk >> 16);
        }
    }
    __syncthreads();

    // ---------------- fc2: MFMA (M=16, K=64, N=64), B from ws ----------------
    {
        const int o = wv * 16 + n;
        floatx4 a2 = (floatx4){bias2, bias2, bias2, bias2};
        const uint4v* f2q = (const uint4v*)(ws + (size_t)l * WSL + 15360);
        #pragma unroll
        for (int ks = 0; ks < 2; ++ks) {
            half8 av = *(const half8*)(USH + O_POOL2 + n * 72 + ks * 32 + quad * 8);
            uint4v bw = f2q[o * 9 + ks * 4 + quad];
            a2 = __builtin_amdgcn_mfma_f32_16x16x32_f16(av, __builtin_bit_cast(half8, bw), a2, 0, 0, 0);
        }
        #pragma unroll
        for (int i = 0; i < 2; ++i) {
            unsigned pk = cvtpk(fmaxf(a2[2 * i], 0.f), fmaxf(a2[2 * i + 1], 0.f));
            USH[O_G2 + (quad * 4 + 2 * i)     * 72 + o] = (unsigned short)(pk & 0xffffu);
            USH[O_G2 + (quad * 4 + 2 * i + 1) * 72 + o] = (unsigned short)(pk >> 16);
        }
    }
    __syncthreads();

    // ---------------- fc3 (K=64) + output ----------------
    if (t < 16) {
        float a = fb3[l];
        const float* w3 = fw3 + (size_t)l * 64;
        #pragma unroll
        for (int c4 = 0; c4 < 16; ++c4) {
            uint2 u2 = *(const uint2*)(USH + O_G2 + t * 72 + c4 * 4);
            float4 w = *(const float4*)(w3 + c4 * 4);
            a += hlo16((unsigned short)(u2.x & 0xffff)) * w.x
               + hlo16((unsigned short)(u2.x >> 16))    * w.y
               + hlo16((unsigned short)(u2.y & 0xffff)) * w.z
               + hlo16((unsigned short)(u2.y >> 16))    * w.w;
        }
        out[(size_t)(b0 + t) * LNUM + l] = a;
    }
}

extern "C" void kernel_launch(void* const* d_in, const int* in_sizes, int n_in,
                              void* d_out, int out_size, void* d_ws, size_t ws_size,
                              hipStream_t stream) {
    const float* zs  = (const float*)d_in[0];
    const float* w1  = (const float*)d_in[1];
    const float* w2  = (const float*)d_in[2];
    const float* fw1 = (const float*)d_in[3];
    const float* fb1 = (const float*)d_in[4];
    const float* fw2 = (const float*)d_in[5];
    const float* fb2 = (const float*)d_in[6];
    const float* fw3 = (const float*)d_in[7];
    const float* fb3 = (const float*)d_in[8];
    float* out = (float*)d_out;
    unsigned short* ws = (unsigned short*)d_ws;

    hipLaunchKernelGGL(prep, dim3(LNUM, 3), dim3(256), 0, stream, w2, fw1, fw2, ws);
    hipLaunchKernelGGL(fused_nn, dim3(LNUM * NBT), dim3(256), 0, stream,
                       zs, w1, fb1, fb2, fw3, fb3, ws, out);
}